// Round 1
// baseline (585.867 us; speedup 1.0000x reference)
//
#include <hip/hip_runtime.h>

// ---------------------------------------------------------------------------
// MultiheadAttention (B=4, S=8192, E=1024, H=16, D=64) — fp32 baseline.
//
// Reference semantics (faithful to the quirky reshape):
//   q = x @ Wq.T + bq           -> (B, S, 64)
//   split: Qh[b,h,i,d] = q[b, i*16 + h, d], i in [0,512)   (S' = S/H = 512)
//   scores = Qh @ Kh^T / 8 ; P = softmax(scores, axis=-1)
//   ctx[b,i,h*64+d] = (P @ Vh)[b,h,i,d]                    -> (B, 512, 1024)
//   out = ctx @ Wo.T + bo                                  -> (B, 512, 1024)
// ---------------------------------------------------------------------------

#define TK 16

// C[m][n] = alpha * ( sum_k A[m][k] * (BT ? B[n][k] : B[k][n]) + bias[n] )
// 64x64 block tile, 256 threads, 4x4 micro-tile per thread.
// Per-z pointer offset: z decomposed as (z>>4, z&15) with separate strides,
// because the (b,h) offset b*524288 + h*64 is not linear in z = b*16+h.
template <bool BT>
__global__ __launch_bounds__(256) void gemm64(
    const float* __restrict__ A, long lda, long sAzH, long sAzL,
    const float* __restrict__ B, long ldb, long sBzH, long sBzL,
    const float* __restrict__ bias,
    float* __restrict__ C, long ldc, long sCzH, long sCzL,
    int K, float alpha)
{
    __shared__ float As[TK][68];   // [k][m], +4 pad keeps b128 reads clean
    __shared__ float Bs[TK][68];   // [k][n]

    const int tid = threadIdx.x;
    const int tx = tid & 15, ty = tid >> 4;
    const long m0 = (long)blockIdx.x * 64;
    const long n0 = (long)blockIdx.y * 64;
    const int zH = blockIdx.z >> 4, zL = blockIdx.z & 15;
    A += zH * sAzH + zL * sAzL;
    B += zH * sBzH + zL * sBzL;
    C += zH * sCzH + zL * sCzL;

    // Staging coords: 64 rows x 16 k per tile, one float4 per thread.
    const int ar = tid >> 2;           // 0..63
    const int ak = (tid & 3) * 4;      // 0,4,8,12
    const int bk = tid >> 4;           // 0..15  (NN layout)
    const int bn = (tid & 15) * 4;     // 0..60

    float acc[4][4] = {};

    for (int k0 = 0; k0 < K; k0 += TK) {
        float4 av = *(const float4*)(A + (m0 + ar) * lda + (k0 + ak));
        float4 bv;
        if (BT) bv = *(const float4*)(B + (n0 + ar) * ldb + (k0 + ak));
        else    bv = *(const float4*)(B + (long)(k0 + bk) * ldb + (n0 + bn));

        __syncthreads();   // previous iteration's readers done before overwrite
        As[ak + 0][ar] = av.x; As[ak + 1][ar] = av.y;
        As[ak + 2][ar] = av.z; As[ak + 3][ar] = av.w;
        if (BT) {
            Bs[ak + 0][ar] = bv.x; Bs[ak + 1][ar] = bv.y;
            Bs[ak + 2][ar] = bv.z; Bs[ak + 3][ar] = bv.w;
        } else {
            *(float4*)&Bs[bk][bn] = bv;
        }
        __syncthreads();

        #pragma unroll
        for (int kk = 0; kk < TK; ++kk) {
            float4 a4 = *(const float4*)&As[kk][ty * 4];
            float4 b4 = *(const float4*)&Bs[kk][tx * 4];
            float ai[4] = {a4.x, a4.y, a4.z, a4.w};
            float bj[4] = {b4.x, b4.y, b4.z, b4.w};
            #pragma unroll
            for (int i = 0; i < 4; ++i)
                #pragma unroll
                for (int j = 0; j < 4; ++j)
                    acc[i][j] += ai[i] * bj[j];
        }
    }

    #pragma unroll
    for (int i = 0; i < 4; ++i) {
        const long row = m0 + ty * 4 + i;
        float4 o;
        float* po = &o.x;
        #pragma unroll
        for (int j = 0; j < 4; ++j) {
            const long col = n0 + tx * 4 + j;
            float v = acc[i][j];
            if (bias) v += bias[col];
            po[j] = v * alpha;
        }
        *(float4*)(C + row * ldc + n0 + tx * 4) = o;
    }
}

// In-place row softmax, rows of length 512. One wave per row, 4 rows/block.
__global__ __launch_bounds__(256) void softmax512(float* __restrict__ S)
{
    const long row = (long)blockIdx.x * 4 + (threadIdx.x >> 6);
    const int lane = threadIdx.x & 63;
    float* p = S + row * 512;

    float e[8];
    float m = -1e30f;
    #pragma unroll
    for (int j = 0; j < 8; ++j) { e[j] = p[lane + 64 * j]; m = fmaxf(m, e[j]); }
    #pragma unroll
    for (int off = 32; off; off >>= 1) m = fmaxf(m, __shfl_xor(m, off, 64));
    float s = 0.f;
    #pragma unroll
    for (int j = 0; j < 8; ++j) { e[j] = __expf(e[j] - m); s += e[j]; }
    #pragma unroll
    for (int off = 32; off; off >>= 1) s += __shfl_xor(s, off, 64);
    const float inv = 1.0f / s;
    #pragma unroll
    for (int j = 0; j < 8; ++j) p[lane + 64 * j] = e[j] * inv;
}

extern "C" void kernel_launch(void* const* d_in, const int* in_sizes, int n_in,
                              void* d_out, int out_size, void* d_ws, size_t ws_size,
                              hipStream_t stream)
{
    const float* x  = (const float*)d_in[0];
    const float* Wq = (const float*)d_in[1];
    const float* bq = (const float*)d_in[2];
    const float* Wk = (const float*)d_in[3];
    const float* bk = (const float*)d_in[4];
    const float* Wv = (const float*)d_in[5];
    const float* bv = (const float*)d_in[6];
    const float* Wo = (const float*)d_in[7];
    const float* bo = (const float*)d_in[8];
    float* out = (float*)d_out;
    float* ws  = (float*)d_ws;

    const long PROJ = 4L * 8192 * 64;        // 2,097,152 floats (8 MB)
    const long SCB  = 16L * 512 * 512;       // scores per batch: 4,194,304 floats
    float* qp  = ws;
    float* kp  = qp + PROJ;
    float* vp  = kp + PROJ;
    float* ctx = vp + PROJ;
    float* sc  = ctx + PROJ;

    const dim3 blk(256);

    // --- QKV projections: M=32768, N=64, K=1024 (1/sqrt(64) folded into Q) ---
    gemm64<true><<<dim3(512, 1, 1), blk, 0, stream>>>(
        x, 1024, 0, 0,  Wq, 1024, 0, 0,  bq,  qp, 64, 0, 0,  1024, 0.125f);
    gemm64<true><<<dim3(512, 1, 1), blk, 0, stream>>>(
        x, 1024, 0, 0,  Wk, 1024, 0, 0,  bk,  kp, 64, 0, 0,  1024, 1.0f);
    gemm64<true><<<dim3(512, 1, 1), blk, 0, stream>>>(
        x, 1024, 0, 0,  Wv, 1024, 0, 0,  bv,  vp, 64, 0, 0,  1024, 1.0f);

    const bool batched = ws_size >= (size_t)(4 * PROJ + 64L * 512 * 512) * 4;  // ~96 MB

    if (batched) {
        // z = b*16 + h over all 64 (b,h) pairs; head offset in qp/kp/vp is
        // b*524288 + h*64 (rows strided by 1024 = 16 heads * 64).
        gemm64<true><<<dim3(8, 8, 64), blk, 0, stream>>>(
            qp, 1024, 524288, 64,  kp, 1024, 524288, 64,  nullptr,
            sc, 512, 4194304, 262144,  64, 1.0f);
        softmax512<<<8192, blk, 0, stream>>>(sc);
        gemm64<false><<<dim3(8, 1, 64), blk, 0, stream>>>(
            sc, 512, 4194304, 262144,  vp, 1024, 524288, 64,  nullptr,
            ctx, 1024, 524288, 64,  512, 1.0f);
    } else {
        for (int b = 0; b < 4; ++b) {
            const long ob = (long)b * 524288;
            gemm64<true><<<dim3(8, 8, 16), blk, 0, stream>>>(
                qp + ob, 1024, 0, 64,  kp + ob, 1024, 0, 64,  nullptr,
                sc, 512, 0, 262144,  64, 1.0f);
            softmax512<<<2048, blk, 0, stream>>>(sc);
            gemm64<false><<<dim3(8, 1, 16), blk, 0, stream>>>(
                sc, 512, 0, 262144,  vp + ob, 1024, 0, 64,  nullptr,
                ctx + ob, 1024, 0, 64,  512, 1.0f);
        }
    }

    // --- Output projection: M=2048, N=1024, K=1024 ---
    gemm64<true><<<dim3(32, 16, 1), blk, 0, stream>>>(
        ctx, 1024, 0, 0,  Wo, 1024, 0, 0,  bo,  out, 1024, 0, 0,  1024, 1.0f);
}

// Round 2
// 302.386 us; speedup vs baseline: 1.9375x; 1.9375x over previous
//
#include <hip/hip_runtime.h>

// ---------------------------------------------------------------------------
// MultiheadAttention (B=4, S=8192, E=1024, H=16, D=64) — bf16 MFMA version.
//
//   qkv = x @ [Wq*0.125 | Wk | Wv]^T + [bq*0.125 | bk | bv]   (bf16, 32768x192)
//   Qh[b,h,i,d] = qkv[b*8192 + i*16 + h][d]      (S' = 512)
//   sc = Qh @ Kh^T (fp32) ; P = softmax(sc) (bf16)
//   ctx[b*512+i][h*64+d] = (P @ Vh)  (bf16)   via Vt = Vh^T
//   out = ctx @ Wo^T + bo (fp32)
//
// MFMA 16x16x32 bf16 layouts (m89/m91-verified):
//   A frag: lane q*16+r holds A[m=r][k=q*8+j], j=0..7   (8 bf16, contiguous k)
//   B frag: lane q*16+r holds B[n=r][k=q*8+j]           (B given n-major)
//   C/D   : lane q*16+r holds D[row=q*4+e][col=r], e=0..3
// LDS staging is pre-swizzled into fragment order so frag reads are
// lane-contiguous ds_read_b128 (conflict-free).
// ---------------------------------------------------------------------------

typedef unsigned short u16;
typedef __attribute__((ext_vector_type(8))) short short8;
typedef __attribute__((ext_vector_type(4))) float f32x4;

__device__ inline u16 f2bf(float f) {
    union { float f; unsigned u; } v; v.f = f;
    unsigned u = v.u;
    return (u16)((u + 0x7fffu + ((u >> 16) & 1u)) >> 16);  // RNE
}

// ---------------------------------------------------------------------------
// Weight/bias conversion: Wqkv bf16 [192][1024] (Wq pre-scaled by 0.125),
// qkvb fp32 [192], Wob bf16 [1024][1024].
// ---------------------------------------------------------------------------
__global__ __launch_bounds__(256) void convw(
    const float* __restrict__ Wq, const float* __restrict__ bq,
    const float* __restrict__ Wk, const float* __restrict__ bk,
    const float* __restrict__ Wv, const float* __restrict__ bv,
    const float* __restrict__ Wo,
    u16* __restrict__ Wqkv, float* __restrict__ qkvb, u16* __restrict__ Wob)
{
    const int idx = blockIdx.x * 256 + threadIdx.x;   // 0 .. 1048575
    Wob[idx] = f2bf(Wo[idx]);
    if (idx < 196608) {
        const int row = idx >> 10, k = idx & 1023;
        float v = (row < 64)  ? Wq[row * 1024 + k] * 0.125f
                : (row < 128) ? Wk[(row - 64) * 1024 + k]
                              : Wv[(row - 128) * 1024 + k];
        Wqkv[idx] = f2bf(v);
    }
    if (idx < 192) {
        qkvb[idx] = (idx < 64) ? bq[idx] * 0.125f
                  : (idx < 128) ? bk[idx - 64] : bv[idx - 128];
    }
}

// ---------------------------------------------------------------------------
// Fused QKV projection: C[32768][192] bf16 = bf16(A[32768][1024] fp32) @ W^T.
// 64-row tile per block, each of 4 waves does one 16-row m-tile x 192 cols.
// ---------------------------------------------------------------------------
__global__ __launch_bounds__(256) void qkv_gemm(
    const float* __restrict__ X, const u16* __restrict__ W,
    const float* __restrict__ bias, u16* __restrict__ Out)
{
    __shared__ short8 As[4 * 64];    // 4 m-tiles, frag order
    __shared__ short8 Bs[12 * 64];   // 12 n-tiles

    const int tid = threadIdx.x;
    const int lane = tid & 63, wid = tid >> 6;
    const long m0 = (long)blockIdx.x * 64;

    const int ra = tid >> 2;                 // 0..63 (row within tile)
    const int ka = tid & 3;                  // k-octet
    const int aslot = (ra >> 4) * 64 + ka * 16 + (ra & 15);
    const float* px = X + (m0 + ra) * 1024 + ka * 8;

    f32x4 acc[12] = {};

    for (int k0 = 0; k0 < 1024; k0 += 32) {
        float4 x0 = *(const float4*)(px + k0);
        float4 x1 = *(const float4*)(px + k0 + 4);
        short8 av;
        av[0] = (short)f2bf(x0.x); av[1] = (short)f2bf(x0.y);
        av[2] = (short)f2bf(x0.z); av[3] = (short)f2bf(x0.w);
        av[4] = (short)f2bf(x1.x); av[5] = (short)f2bf(x1.y);
        av[6] = (short)f2bf(x1.z); av[7] = (short)f2bf(x1.w);
        short8 bv[3];
        #pragma unroll
        for (int i = 0; i < 3; ++i) {
            const int c = tid + 256 * i;
            bv[i] = *(const short8*)(W + (long)(c >> 2) * 1024 + k0 + (c & 3) * 8);
        }
        __syncthreads();
        As[aslot] = av;
        #pragma unroll
        for (int i = 0; i < 3; ++i) {
            const int c = tid + 256 * i, rb = c >> 2;
            Bs[(rb >> 4) * 64 + (c & 3) * 16 + (rb & 15)] = bv[i];
        }
        __syncthreads();
        short8 af = As[wid * 64 + lane];
        #pragma unroll
        for (int nt = 0; nt < 12; ++nt)
            acc[nt] = __builtin_amdgcn_mfma_f32_16x16x32_bf16(
                af, Bs[nt * 64 + lane], acc[nt], 0, 0, 0);
    }

    const int q = lane >> 4, r = lane & 15;
    #pragma unroll
    for (int nt = 0; nt < 12; ++nt) {
        const int col = nt * 16 + r;
        const float badd = bias[col];
        #pragma unroll
        for (int e = 0; e < 4; ++e) {
            const long row = m0 + wid * 16 + q * 4 + e;
            Out[row * 192 + col] = f2bf(acc[nt][e] + badd);
        }
    }
}

// ---------------------------------------------------------------------------
// Generic bf16 MFMA GEMM: C[m][n] = A[m][k] @ B[n][k]^T (+ bias[n]).
// 64x64 tile, 4 waves in 2x2, each wave 32x32 (2x2 MFMA tiles). BK=32.
// z decomposed as (z>>4, z&15) with separate strides.
// ---------------------------------------------------------------------------
template <typename TC>
__global__ __launch_bounds__(256) void gemm_bf(
    const u16* __restrict__ A, long lda, long sAzH, long sAzL,
    const u16* __restrict__ B, long ldb, long sBzH, long sBzL,
    const float* __restrict__ bias,
    TC* __restrict__ C, long ldc, long sCzH, long sCzL,
    int K)
{
    __shared__ short8 As[4 * 64];
    __shared__ short8 Bs[4 * 64];

    const int tid = threadIdx.x;
    const int lane = tid & 63, wid = tid >> 6;
    const long m0 = (long)blockIdx.x * 64, n0 = (long)blockIdx.y * 64;
    const int zH = blockIdx.z >> 4, zL = blockIdx.z & 15;
    A += zH * sAzH + zL * sAzL;
    B += zH * sBzH + zL * sBzL;
    C += zH * sCzH + zL * sCzL;

    const int r4 = tid >> 2, k8 = tid & 3;
    const int slot = (r4 >> 4) * 64 + k8 * 16 + (r4 & 15);
    const u16* pa = A + (m0 + r4) * lda + k8 * 8;
    const u16* pb = B + (n0 + r4) * ldb + k8 * 8;

    const int mh = (wid >> 1) * 2;   // m-tile base for this wave
    const int nh = (wid & 1) * 2;    // n-tile base

    f32x4 acc[2][2] = {};

    for (int k0 = 0; k0 < K; k0 += 32) {
        short8 av = *(const short8*)(pa + k0);
        short8 bv = *(const short8*)(pb + k0);
        __syncthreads();
        As[slot] = av; Bs[slot] = bv;
        __syncthreads();
        short8 af0 = As[(mh + 0) * 64 + lane], af1 = As[(mh + 1) * 64 + lane];
        short8 bf0 = Bs[(nh + 0) * 64 + lane], bf1 = Bs[(nh + 1) * 64 + lane];
        acc[0][0] = __builtin_amdgcn_mfma_f32_16x16x32_bf16(af0, bf0, acc[0][0], 0, 0, 0);
        acc[0][1] = __builtin_amdgcn_mfma_f32_16x16x32_bf16(af0, bf1, acc[0][1], 0, 0, 0);
        acc[1][0] = __builtin_amdgcn_mfma_f32_16x16x32_bf16(af1, bf0, acc[1][0], 0, 0, 0);
        acc[1][1] = __builtin_amdgcn_mfma_f32_16x16x32_bf16(af1, bf1, acc[1][1], 0, 0, 0);
    }

    const int q = lane >> 4, r = lane & 15;
    #pragma unroll
    for (int i = 0; i < 2; ++i) {
        #pragma unroll
        for (int j = 0; j < 2; ++j) {
            const long col = n0 + (nh + j) * 16 + r;
            const float badd = bias ? bias[col] : 0.0f;
            #pragma unroll
            for (int e = 0; e < 4; ++e) {
                const long row = m0 + (mh + i) * 16 + q * 4 + e;
                float v = acc[i][j][e] + badd;
                if constexpr (sizeof(TC) == 2) C[row * ldc + col] = (TC)f2bf(v);
                else                           C[row * ldc + col] = v;
            }
        }
    }
}

// ---------------------------------------------------------------------------
// V transpose: Vt[bh][d][i] <- qkv[b*8192 + i*16 + h][128 + d]
// ---------------------------------------------------------------------------
__global__ __launch_bounds__(256) void vtrans(
    const u16* __restrict__ qkv, u16* __restrict__ Vt)
{
    __shared__ u16 T[64][68];
    const int bh = blockIdx.x, b = bh >> 4, h = bh & 15;
    const int i0 = blockIdx.y * 64;
    const int tid = threadIdx.x;

    #pragma unroll
    for (int it = 0; it < 2; ++it) {
        const int c = tid + 256 * it;               // 0..511
        const int il = c >> 3, d8 = (c & 7) * 8;
        short8 v = *(const short8*)(qkv +
            ((long)b * 8192 + (long)(i0 + il) * 16 + h) * 192 + 128 + d8);
        #pragma unroll
        for (int j = 0; j < 8; ++j) T[d8 + j][il] = (u16)v[j];
    }
    __syncthreads();
    #pragma unroll
    for (int it = 0; it < 2; ++it) {
        const int c = tid + 256 * it;
        const int dl = c >> 3, i8 = (c & 7) * 8;
        short8 o;
        #pragma unroll
        for (int j = 0; j < 8; ++j) o[j] = (short)T[dl][i8 + j];
        *(short8*)(Vt + ((long)bh * 64 + dl) * 512 + i0 + i8) = o;
    }
}

// ---------------------------------------------------------------------------
// Row softmax over 512, fp32 in -> bf16 out. One wave per row.
// ---------------------------------------------------------------------------
__global__ __launch_bounds__(256) void softmax_bf(
    const float* __restrict__ S, u16* __restrict__ P)
{
    const long row = (long)blockIdx.x * 4 + (threadIdx.x >> 6);
    const int lane = threadIdx.x & 63;
    const float* p = S + row * 512;

    float e[8], m = -1e30f;
    #pragma unroll
    for (int j = 0; j < 8; ++j) { e[j] = p[lane + 64 * j]; m = fmaxf(m, e[j]); }
    #pragma unroll
    for (int off = 32; off; off >>= 1) m = fmaxf(m, __shfl_xor(m, off, 64));
    float s = 0.f;
    #pragma unroll
    for (int j = 0; j < 8; ++j) { e[j] = __expf(e[j] - m); s += e[j]; }
    #pragma unroll
    for (int off = 32; off; off >>= 1) s += __shfl_xor(s, off, 64);
    const float inv = 1.0f / s;
    u16* o = P + row * 512;
    #pragma unroll
    for (int j = 0; j < 8; ++j) o[lane + 64 * j] = f2bf(e[j] * inv);
}

// ---------------------------------------------------------------------------
extern "C" void kernel_launch(void* const* d_in, const int* in_sizes, int n_in,
                              void* d_out, int out_size, void* d_ws, size_t ws_size,
                              hipStream_t stream)
{
    const float* x  = (const float*)d_in[0];
    const float* Wq = (const float*)d_in[1];
    const float* bq = (const float*)d_in[2];
    const float* Wk = (const float*)d_in[3];
    const float* bk = (const float*)d_in[4];
    const float* Wv = (const float*)d_in[5];
    const float* bv = (const float*)d_in[6];
    const float* Wo = (const float*)d_in[7];
    const float* bo = (const float*)d_in[8];
    float* out = (float*)d_out;
    char* ws = (char*)d_ws;

    u16*   qkv  = (u16*)(ws);                   // 32768*192*2   = 12,582,912
    u16*   Vt   = (u16*)(ws + 12582912);        // 64*64*512*2   =  4,194,304
    u16*   Wqkv = (u16*)(ws + 16777216);        // 192*1024*2    =    393,216
    u16*   Wob  = (u16*)(ws + 17170432);        // 1024*1024*2   =  2,097,152
    float* qkvb = (float*)(ws + 19267584);      // 192*4         =        768
    u16*   ctx  = (u16*)(ws + 19268352);        // 2048*1024*2   =  4,194,304
    float* sc   = (float*)(ws + 23462656);      // batched 64 MB / per-b 16 MB

    const size_t need_batched = 23462656ull + 67108864ull + 33554432ull; // ~124 MB
    const bool batched = ws_size >= need_batched;

    convw<<<4096, 256, 0, stream>>>(Wq, bq, Wk, bk, Wv, bv, Wo, Wqkv, qkvb, Wob);
    qkv_gemm<<<512, 256, 0, stream>>>(x, Wqkv, qkvb, qkv);
    vtrans<<<dim3(64, 8), 256, 0, stream>>>(qkv, Vt);

    if (batched) {
        u16* P = (u16*)(ws + 23462656 + 67108864);
        // scores: z = b*16+h; Q rows strided 16*192=3072, head offset h*192
        gemm_bf<float><<<dim3(8, 8, 64), 256, 0, stream>>>(
            qkv,      3072, 8192L * 192, 192,
            qkv + 64, 3072, 8192L * 192, 192,
            nullptr,
            sc, 512, 16L * 262144, 262144, 64);
        softmax_bf<<<8192, 256, 0, stream>>>(sc, P);
        gemm_bf<u16><<<dim3(8, 1, 64), 256, 0, stream>>>(
            P,  512, 16L * 262144, 262144,
            Vt, 512, 16L * 32768,  32768,
            nullptr,
            ctx, 1024, 524288, 64, 512);
    } else {
        u16* P = (u16*)(ws + 23462656 + 16777216);
        for (int b = 0; b < 4; ++b) {
            const u16* qb = qkv + (long)b * 8192 * 192;
            gemm_bf<float><<<dim3(8, 8, 16), 256, 0, stream>>>(
                qb,      3072, 0, 192,
                qb + 64, 3072, 0, 192,
                nullptr,
                sc, 512, 0, 262144, 64);
            softmax_bf<<<2048, 256, 0, stream>>>(sc, P);
            gemm_bf<u16><<<dim3(8, 1, 16), 256, 0, stream>>>(
                P,  512, 0, 262144,
                Vt + (long)b * 524288, 512, 0, 32768,
                nullptr,
                ctx + (long)b * 524288, 1024, 0, 64, 512);
        }
    }

    gemm_bf<float><<<dim3(32, 16, 1), 256, 0, stream>>>(
        ctx, 1024, 0, 0,
        Wob, 1024, 0, 0,
        bo,
        out, 1024, 0, 0, 1024);
}

// Round 3
// 285.000 us; speedup vs baseline: 2.0557x; 1.0610x over previous
//
#include <hip/hip_runtime.h>
#include <hip/hip_bf16.h>

// ---------------------------------------------------------------------------
// MultiheadAttention (B=4, S=8192, E=1024, H=16, D=64) — bf16 MFMA + fused
// flash attention.
//
//   qkv = x @ [Wq*0.125 | Wk | Wv]^T + [bq*0.125 | bk | bv]   (bf16, 32768x192)
//   Qh[b,h,i,d] = qkv[b*8192 + i*16 + h][d]      (S' = 512)
//   fused: ctx[b*512+i][h*64+d] = softmax(Qh Kh^T) @ Vh   (no score buffer)
//   out = ctx @ Wo^T + bo (fp32)
//
// MFMA 16x16x32 bf16 layouts (m89/m91-verified):
//   A frag: lane q*16+r holds A[m=r][k=q*8+j]
//   B frag: lane q*16+r holds B[n=r][k=q*8+j]   (B n-major)
//   C/D   : lane q*16+r holds D[row=q*4+e][col=r]
// ---------------------------------------------------------------------------

typedef unsigned short u16;
typedef __attribute__((ext_vector_type(8))) short short8;
typedef __attribute__((ext_vector_type(4))) float f32x4;

__device__ inline u16 f2bf(float f) {
    union { float f; unsigned u; } v; v.f = f;
    unsigned u = v.u;
    return (u16)((u + 0x7fffu + ((u >> 16) & 1u)) >> 16);  // RNE
}
__device__ inline unsigned pack_bf2(float a, float b) {
    union { __hip_bfloat162 h; unsigned u; } v;
    v.h = __float22bfloat162_rn(float2{a, b});
    return v.u;
}

// ---------------------------------------------------------------------------
// Weight/bias conversion.
// ---------------------------------------------------------------------------
__global__ __launch_bounds__(256) void convw(
    const float* __restrict__ Wq, const float* __restrict__ bq,
    const float* __restrict__ Wk, const float* __restrict__ bk,
    const float* __restrict__ Wv, const float* __restrict__ bv,
    const float* __restrict__ Wo,
    u16* __restrict__ Wqkv, float* __restrict__ qkvb, u16* __restrict__ Wob)
{
    const int idx = blockIdx.x * 256 + threadIdx.x;   // 0 .. 1048575
    Wob[idx] = f2bf(Wo[idx]);
    if (idx < 196608) {
        const int row = idx >> 10, k = idx & 1023;
        float v = (row < 64)  ? Wq[row * 1024 + k] * 0.125f
                : (row < 128) ? Wk[(row - 64) * 1024 + k]
                              : Wv[(row - 128) * 1024 + k];
        Wqkv[idx] = f2bf(v);
    }
    if (idx < 192) {
        qkvb[idx] = (idx < 64) ? bq[idx] * 0.125f
                  : (idx < 128) ? bk[idx - 64] : bv[idx - 128];
    }
}

// ---------------------------------------------------------------------------
// Fused QKV projection: C[32768][192] bf16 = bf16(X[32768][1024] fp32) @ W^T.
// ---------------------------------------------------------------------------
__global__ __launch_bounds__(256) void qkv_gemm(
    const float* __restrict__ X, const u16* __restrict__ W,
    const float* __restrict__ bias, u16* __restrict__ Out)
{
    __shared__ short8 As[4 * 64];
    __shared__ short8 Bs[12 * 64];

    const int tid = threadIdx.x;
    const int lane = tid & 63, wid = tid >> 6;
    const long m0 = (long)blockIdx.x * 64;

    const int ra = tid >> 2;
    const int ka = tid & 3;
    const int aslot = (ra >> 4) * 64 + ka * 16 + (ra & 15);
    const float* px = X + (m0 + ra) * 1024 + ka * 8;

    f32x4 acc[12] = {};

    for (int k0 = 0; k0 < 1024; k0 += 32) {
        float4 x0 = *(const float4*)(px + k0);
        float4 x1 = *(const float4*)(px + k0 + 4);
        union { short8 s; unsigned u[4]; } av;
        av.u[0] = pack_bf2(x0.x, x0.y);
        av.u[1] = pack_bf2(x0.z, x0.w);
        av.u[2] = pack_bf2(x1.x, x1.y);
        av.u[3] = pack_bf2(x1.z, x1.w);
        short8 bv[3];
        #pragma unroll
        for (int i = 0; i < 3; ++i) {
            const int c = tid + 256 * i;
            bv[i] = *(const short8*)(W + (long)(c >> 2) * 1024 + k0 + (c & 3) * 8);
        }
        __syncthreads();
        As[aslot] = av.s;
        #pragma unroll
        for (int i = 0; i < 3; ++i) {
            const int c = tid + 256 * i, rb = c >> 2;
            Bs[(rb >> 4) * 64 + (c & 3) * 16 + (rb & 15)] = bv[i];
        }
        __syncthreads();
        short8 af = As[wid * 64 + lane];
        #pragma unroll
        for (int nt = 0; nt < 12; ++nt)
            acc[nt] = __builtin_amdgcn_mfma_f32_16x16x32_bf16(
                af, Bs[nt * 64 + lane], acc[nt], 0, 0, 0);
    }

    const int q = lane >> 4, r = lane & 15;
    #pragma unroll
    for (int nt = 0; nt < 12; ++nt) {
        const int col = nt * 16 + r;
        const float badd = bias[col];
        #pragma unroll
        for (int e = 0; e < 4; ++e) {
            const long row = m0 + wid * 16 + q * 4 + e;
            Out[row * 192 + col] = f2bf(acc[nt][e] + badd);
        }
    }
}

// ---------------------------------------------------------------------------
// V transpose: Vt[bh*64 + d][i] <- qkv[b*8192 + i*16 + h][128 + d]
// ---------------------------------------------------------------------------
__global__ __launch_bounds__(256) void vtrans(
    const u16* __restrict__ qkv, u16* __restrict__ Vt)
{
    __shared__ u16 T[64][68];
    const int bh = blockIdx.x, b = bh >> 4, h = bh & 15;
    const int i0 = blockIdx.y * 64;
    const int tid = threadIdx.x;

    #pragma unroll
    for (int it = 0; it < 2; ++it) {
        const int c = tid + 256 * it;
        const int il = c >> 3, d8 = (c & 7) * 8;
        short8 v = *(const short8*)(qkv +
            ((long)b * 8192 + (long)(i0 + il) * 16 + h) * 192 + 128 + d8);
        #pragma unroll
        for (int j = 0; j < 8; ++j) T[d8 + j][il] = (u16)v[j];
    }
    __syncthreads();
    #pragma unroll
    for (int it = 0; it < 2; ++it) {
        const int c = tid + 256 * it;
        const int dl = c >> 3, i8 = (c & 7) * 8;
        short8 o;
        #pragma unroll
        for (int j = 0; j < 8; ++j) o[j] = (short)T[dl][i8 + j];
        *(short8*)(Vt + ((long)bh * 64 + dl) * 512 + i0 + i8) = o;
    }
}

// ---------------------------------------------------------------------------
// Fused flash attention: one block per (q-tile, bh); 4 waves, 16 Q-rows each.
// Online softmax in registers; P goes C-layout -> A-frag layout through a
// wave-private LDS buffer (stride 72 u16: conflict-free writes, aligned b128
// frag reads). K/V fragments load straight from global (L2-hot).
// ---------------------------------------------------------------------------
__global__ __launch_bounds__(256) void attn_flash(
    const u16* __restrict__ qkv, const u16* __restrict__ Vt,
    u16* __restrict__ ctx)
{
    __shared__ u16 Plds[4][16 * 72];   // 2304 B per wave, wave-private

    const int tid = threadIdx.x, lane = tid & 63, wid = tid >> 6;
    const int q = lane >> 4, r = lane & 15;
    const int qt = blockIdx.x;         // 0..7
    const int bh = blockIdx.y;         // 0..63
    const int b = bh >> 4, h = bh & 15;

    const long qrowbase = (long)b * 8192 + h;   // qkv row = qrowbase + i*16

    // Q A-fragments for this wave's 16 rows (k = d = 0..63 -> 2 frags)
    short8 Qf0, Qf1;
    {
        const int i = qt * 64 + wid * 16 + r;
        const u16* p = qkv + (qrowbase + (long)i * 16) * 192 + q * 8;
        Qf0 = *(const short8*)(p);
        Qf1 = *(const short8*)(p + 32);
    }

    f32x4 O[4] = {};
    float mrun[4] = {-1e30f, -1e30f, -1e30f, -1e30f};
    float lrun[4] = {};
    u16* Pw = &Plds[wid][0];

    for (int j0 = 0; j0 < 512; j0 += 64) {
        // ---- scores chunk S[16 rows][64 keys] ----
        f32x4 S[4];
        #pragma unroll
        for (int ct = 0; ct < 4; ++ct) {
            const int key = j0 + ct * 16 + r;
            const u16* p = qkv + (qrowbase + (long)key * 16) * 192 + 64 + q * 8;
            short8 k0 = *(const short8*)(p);
            short8 k1 = *(const short8*)(p + 32);
            f32x4 s = {};
            s = __builtin_amdgcn_mfma_f32_16x16x32_bf16(Qf0, k0, s, 0, 0, 0);
            s = __builtin_amdgcn_mfma_f32_16x16x32_bf16(Qf1, k1, s, 0, 0, 0);
            S[ct] = s;
        }
        // ---- online softmax update (per row = (q, e); reduce over r) ----
        #pragma unroll
        for (int e = 0; e < 4; ++e) {
            float mc = fmaxf(fmaxf(S[0][e], S[1][e]), fmaxf(S[2][e], S[3][e]));
            #pragma unroll
            for (int off = 1; off < 16; off <<= 1)
                mc = fmaxf(mc, __shfl_xor(mc, off, 64));
            const float mnew = fmaxf(mrun[e], mc);
            const float alpha = __expf(mrun[e] - mnew);
            mrun[e] = mnew;
            float se = 0.f;
            #pragma unroll
            for (int ct = 0; ct < 4; ++ct) {
                const float pv = __expf(S[ct][e] - mnew);
                S[ct][e] = pv; se += pv;
            }
            #pragma unroll
            for (int off = 1; off < 16; off <<= 1)
                se += __shfl_xor(se, off, 64);
            lrun[e] = lrun[e] * alpha + se;
            #pragma unroll
            for (int nt = 0; nt < 4; ++nt) O[nt][e] *= alpha;
        }
        // ---- P: C-layout -> LDS [m][k] (stride 72) -> A-frags ----
        #pragma unroll
        for (int e = 0; e < 4; ++e)
            #pragma unroll
            for (int ct = 0; ct < 4; ++ct)
                Pw[(q * 4 + e) * 72 + ct * 16 + r] = f2bf(S[ct][e]);
        short8 Pf0 = *(const short8*)(Pw + r * 72 + q * 8);
        short8 Pf1 = *(const short8*)(Pw + r * 72 + 32 + q * 8);
        // ---- O += P @ V  (V^T n-major from Vt) ----
        #pragma unroll
        for (int nt = 0; nt < 4; ++nt) {
            const u16* p = Vt + ((long)bh * 64 + nt * 16 + r) * 512 + j0 + q * 8;
            short8 v0 = *(const short8*)(p);
            short8 v1 = *(const short8*)(p + 32);
            O[nt] = __builtin_amdgcn_mfma_f32_16x16x32_bf16(Pf0, v0, O[nt], 0, 0, 0);
            O[nt] = __builtin_amdgcn_mfma_f32_16x16x32_bf16(Pf1, v1, O[nt], 0, 0, 0);
        }
    }

    // ---- epilogue: normalize, write ctx[b*512+i][h*64+d] ----
    #pragma unroll
    for (int e = 0; e < 4; ++e) {
        const float inv = 1.0f / lrun[e];
        const long i = qt * 64 + wid * 16 + q * 4 + e;
        u16* po = ctx + ((long)b * 512 + i) * 1024 + h * 64 + r;
        #pragma unroll
        for (int nt = 0; nt < 4; ++nt)
            po[nt * 16] = f2bf(O[nt][e] * inv);
    }
}

// ---------------------------------------------------------------------------
// bf16 MFMA GEMM (used for the output projection only):
// C[m][n] = A[m][k] @ B[n][k]^T + bias[n].  64x64 tile, 4 waves 2x2.
// ---------------------------------------------------------------------------
__global__ __launch_bounds__(256) void gemm_bf(
    const u16* __restrict__ A, long lda,
    const u16* __restrict__ B, long ldb,
    const float* __restrict__ bias,
    float* __restrict__ C, long ldc, int K)
{
    __shared__ short8 As[4 * 64];
    __shared__ short8 Bs[4 * 64];

    const int tid = threadIdx.x;
    const int lane = tid & 63, wid = tid >> 6;
    const long m0 = (long)blockIdx.x * 64, n0 = (long)blockIdx.y * 64;

    const int r4 = tid >> 2, k8 = tid & 3;
    const int slot = (r4 >> 4) * 64 + k8 * 16 + (r4 & 15);
    const u16* pa = A + (m0 + r4) * lda + k8 * 8;
    const u16* pb = B + (n0 + r4) * ldb + k8 * 8;

    const int mh = (wid >> 1) * 2, nh = (wid & 1) * 2;
    f32x4 acc[2][2] = {};

    for (int k0 = 0; k0 < K; k0 += 32) {
        short8 av = *(const short8*)(pa + k0);
        short8 bv = *(const short8*)(pb + k0);
        __syncthreads();
        As[slot] = av; Bs[slot] = bv;
        __syncthreads();
        short8 af0 = As[(mh + 0) * 64 + lane], af1 = As[(mh + 1) * 64 + lane];
        short8 bf0 = Bs[(nh + 0) * 64 + lane], bf1 = Bs[(nh + 1) * 64 + lane];
        acc[0][0] = __builtin_amdgcn_mfma_f32_16x16x32_bf16(af0, bf0, acc[0][0], 0, 0, 0);
        acc[0][1] = __builtin_amdgcn_mfma_f32_16x16x32_bf16(af0, bf1, acc[0][1], 0, 0, 0);
        acc[1][0] = __builtin_amdgcn_mfma_f32_16x16x32_bf16(af1, bf0, acc[1][0], 0, 0, 0);
        acc[1][1] = __builtin_amdgcn_mfma_f32_16x16x32_bf16(af1, bf1, acc[1][1], 0, 0, 0);
    }

    const int q = lane >> 4, r = lane & 15;
    #pragma unroll
    for (int i = 0; i < 2; ++i)
        #pragma unroll
        for (int j = 0; j < 2; ++j) {
            const long col = n0 + (nh + j) * 16 + r;
            const float badd = bias[col];
            #pragma unroll
            for (int e = 0; e < 4; ++e) {
                const long row = m0 + (mh + i) * 16 + q * 4 + e;
                C[row * ldc + col] = acc[i][j][e] + badd;
            }
        }
}

// ---------------------------------------------------------------------------
extern "C" void kernel_launch(void* const* d_in, const int* in_sizes, int n_in,
                              void* d_out, int out_size, void* d_ws, size_t ws_size,
                              hipStream_t stream)
{
    const float* x  = (const float*)d_in[0];
    const float* Wq = (const float*)d_in[1];
    const float* bq = (const float*)d_in[2];
    const float* Wk = (const float*)d_in[3];
    const float* bk = (const float*)d_in[4];
    const float* Wv = (const float*)d_in[5];
    const float* bv = (const float*)d_in[6];
    const float* Wo = (const float*)d_in[7];
    const float* bo = (const float*)d_in[8];
    float* out = (float*)d_out;
    char* ws = (char*)d_ws;

    u16*   qkv  = (u16*)(ws);                   // 32768*192*2   = 12,582,912
    u16*   Vt   = (u16*)(ws + 12582912);        // 64*64*512*2   =  4,194,304
    u16*   Wqkv = (u16*)(ws + 16777216);        // 192*1024*2    =    393,216
    u16*   Wob  = (u16*)(ws + 17170432);        // 1024*1024*2   =  2,097,152
    float* qkvb = (float*)(ws + 19267584);      // 192*4
    u16*   ctx  = (u16*)(ws + 19268352);        // 2048*1024*2   =  4,194,304

    convw<<<4096, 256, 0, stream>>>(Wq, bq, Wk, bk, Wv, bv, Wo, Wqkv, qkvb, Wob);
    qkv_gemm<<<512, 256, 0, stream>>>(x, Wqkv, qkvb, qkv);
    vtrans<<<dim3(64, 8), 256, 0, stream>>>(qkv, Vt);
    attn_flash<<<dim3(8, 64), 256, 0, stream>>>(qkv, Vt, ctx);
    gemm_bf<<<dim3(32, 16), 256, 0, stream>>>(
        ctx, 1024, Wob, 1024, bo, out, 1024, 1024);
}

// Round 4
// 273.841 us; speedup vs baseline: 2.1394x; 1.0407x over previous
//
#include <hip/hip_runtime.h>
#include <hip/hip_bf16.h>

// ---------------------------------------------------------------------------
// MultiheadAttention (B=4, S=8192, E=1024, H=16, D=64) — bf16 MFMA, async
// global_load_lds staging throughout, fused flash attention.
//
//   qkv = x @ [Wq*0.125 | Wk | Wv]^T + [bq*0.125 | bk | bv]   (bf16, 32768x192)
//   Qh[b,h,i,d] = qkv[b*8192 + i*16 + h][d]      (S' = 512)
//   fused: ctx[b*512+i][h*64+d] = softmax(Qh Kh^T) @ Vh   (no score buffer)
//   out = ctx @ Wo^T + bo (fp32)
//
// MFMA 16x16x32 bf16 layouts (m89/m91-verified):
//   A frag: lane q*16+r holds A[m=r][k=q*8+j]
//   B frag: lane q*16+r holds B[n=r][k=q*8+j]   (B n-major)
//   C/D   : lane q*16+r holds D[row=q*4+e][col=r]
// All LDS tile layouts are frag-order (slot = tile*64 + q*16 + r), staged by
// global_load_lds (dest = wave-uniform base + lane*16 -> conflict-free).
// ---------------------------------------------------------------------------

typedef unsigned short u16;
typedef __attribute__((ext_vector_type(8))) short short8;
typedef __attribute__((ext_vector_type(4))) float f32x4;

__device__ inline u16 f2bf(float f) {
    union { float f; unsigned u; } v; v.f = f;
    unsigned u = v.u;
    return (u16)((u + 0x7fffu + ((u >> 16) & 1u)) >> 16);  // RNE
}
__device__ inline unsigned pack_bf2(float a, float b) {
    union { __hip_bfloat162 h; unsigned u; } v;
    v.h = __float22bfloat162_rn(float2{a, b});
    return v.u;
}
// Async global->LDS, 16 B per lane. LDS dest = wave-uniform base + lane*16.
__device__ __forceinline__ void gld16(void* lds, const void* gptr) {
    __builtin_amdgcn_global_load_lds(
        (const __attribute__((address_space(1))) unsigned int*)gptr,
        (__attribute__((address_space(3))) unsigned int*)lds,
        16, 0, 0);
}

// ---------------------------------------------------------------------------
// Weight/bias conversion.
// ---------------------------------------------------------------------------
__global__ __launch_bounds__(256) void convw(
    const float* __restrict__ Wq, const float* __restrict__ bq,
    const float* __restrict__ Wk, const float* __restrict__ bk,
    const float* __restrict__ Wv, const float* __restrict__ bv,
    const float* __restrict__ Wo,
    u16* __restrict__ Wqkv, float* __restrict__ qkvb, u16* __restrict__ Wob)
{
    const int idx = blockIdx.x * 256 + threadIdx.x;   // 0 .. 1048575
    Wob[idx] = f2bf(Wo[idx]);
    if (idx < 196608) {
        const int row = idx >> 10, k = idx & 1023;
        float v = (row < 64)  ? Wq[row * 1024 + k] * 0.125f
                : (row < 128) ? Wk[(row - 64) * 1024 + k]
                              : Wv[(row - 128) * 1024 + k];
        Wqkv[idx] = f2bf(v);
    }
    if (idx < 192) {
        qkvb[idx] = (idx < 64) ? bq[idx] * 0.125f
                  : (idx < 128) ? bk[idx - 64] : bv[idx - 128];
    }
}

// ---------------------------------------------------------------------------
// Fused QKV projection: qkv[32768][192] bf16 = bf16(X fp32) @ Wqkv^T + b.
// 64-row tile/block; wave w owns m-tile w. A-frags load straight from global
// (each lane's 32B load IS its fragment; register-prefetched across the
// barrier). B staged via global_load_lds, double-buffered, 1 barrier/step.
// ---------------------------------------------------------------------------
__global__ __launch_bounds__(256) void qkv_gemm(
    const float* __restrict__ X, const u16* __restrict__ W,
    const float* __restrict__ bias, u16* __restrict__ Out)
{
    __shared__ short8 Bs[2][768];   // 12 n-tiles x 64 slots, x2 buffers

    const int tid = threadIdx.x;
    const int lane = tid & 63, wid = tid >> 6;
    const int q = lane >> 4, r = lane & 15;
    const long m0 = (long)blockIdx.x * 64;

    // B staging: thread handles slots wid*192 + i*64 + lane, i=0..2
    const u16* wp[3];
    #pragma unroll
    for (int i = 0; i < 3; ++i)
        wp[i] = W + (long)((wid * 3 + i) * 16 + r) * 1024 + q * 8;

    // A direct: this lane's fragment rows
    const float* px = X + (m0 + wid * 16 + r) * 1024 + q * 8;

    f32x4 acc[12] = {};

    // prologue: stage k0=0 into buf 0, prefetch A regs
    #pragma unroll
    for (int i = 0; i < 3; ++i)
        gld16(&Bs[0][wid * 192 + i * 64], wp[i]);
    float4 a0 = *(const float4*)(px);
    float4 a1 = *(const float4*)(px + 4);
    __syncthreads();

    for (int k0 = 0; k0 < 1024; k0 += 32) {
        const int buf = (k0 >> 5) & 1;
        float4 a0n = {}, a1n = {};
        if (k0 + 32 < 1024) {
            #pragma unroll
            for (int i = 0; i < 3; ++i)
                gld16(&Bs[buf ^ 1][wid * 192 + i * 64], wp[i] + k0 + 32);
            a0n = *(const float4*)(px + k0 + 32);
            a1n = *(const float4*)(px + k0 + 36);
        }
        union { short8 s; unsigned u[4]; } af;
        af.u[0] = pack_bf2(a0.x, a0.y);
        af.u[1] = pack_bf2(a0.z, a0.w);
        af.u[2] = pack_bf2(a1.x, a1.y);
        af.u[3] = pack_bf2(a1.z, a1.w);
        #pragma unroll
        for (int nt = 0; nt < 12; ++nt)
            acc[nt] = __builtin_amdgcn_mfma_f32_16x16x32_bf16(
                af.s, Bs[buf][nt * 64 + lane], acc[nt], 0, 0, 0);
        __syncthreads();
        a0 = a0n; a1 = a1n;
    }

    #pragma unroll
    for (int nt = 0; nt < 12; ++nt) {
        const int col = nt * 16 + r;
        const float badd = bias[col];
        #pragma unroll
        for (int e = 0; e < 4; ++e) {
            const long row = m0 + wid * 16 + q * 4 + e;
            Out[row * 192 + col] = f2bf(acc[nt][e] + badd);
        }
    }
}

// ---------------------------------------------------------------------------
// V transpose: Vt[bh*64 + d][i] <- qkv[b*8192 + i*16 + h][128 + d]
// ---------------------------------------------------------------------------
__global__ __launch_bounds__(256) void vtrans(
    const u16* __restrict__ qkv, u16* __restrict__ Vt)
{
    __shared__ u16 T[64][68];
    const int bh = blockIdx.x, b = bh >> 4, h = bh & 15;
    const int i0 = blockIdx.y * 64;
    const int tid = threadIdx.x;

    #pragma unroll
    for (int it = 0; it < 2; ++it) {
        const int c = tid + 256 * it;
        const int il = c >> 3, d8 = (c & 7) * 8;
        short8 v = *(const short8*)(qkv +
            ((long)b * 8192 + (long)(i0 + il) * 16 + h) * 192 + 128 + d8);
        #pragma unroll
        for (int j = 0; j < 8; ++j) T[d8 + j][il] = (u16)v[j];
    }
    __syncthreads();
    #pragma unroll
    for (int it = 0; it < 2; ++it) {
        const int c = tid + 256 * it;
        const int dl = c >> 3, i8 = (c & 7) * 8;
        short8 o;
        #pragma unroll
        for (int j = 0; j < 8; ++j) o[j] = (short)T[dl][i8 + j];
        *(short8*)(Vt + ((long)bh * 64 + dl) * 512 + i0 + i8) = o;
    }
}

// ---------------------------------------------------------------------------
// Fused flash attention: block = (q-tile of 64, bh); 4 waves, 16 Q-rows each.
// K/V chunks (64 keys) staged cooperatively into double-buffered LDS via
// global_load_lds, prefetched one chunk ahead; one barrier per chunk.
// Online softmax in registers; P goes C-layout -> A-frag layout through a
// wave-private LDS buffer (stride 72 u16).
// ---------------------------------------------------------------------------
__global__ __launch_bounds__(256) void attn_flash(
    const u16* __restrict__ qkv, const u16* __restrict__ Vt,
    u16* __restrict__ ctx)
{
    __shared__ short8 Ks[2][512];      // [f*256 + ct*64 + q*16 + r]
    __shared__ short8 Vs[2][512];      // [f*256 + nt*64 + q*16 + r]
    __shared__ u16 Plds[4][16 * 72];   // wave-private P transform

    const int tid = threadIdx.x, lane = tid & 63, wid = tid >> 6;
    const int q = lane >> 4, r = lane & 15;
    const int qt = blockIdx.x;         // 0..7
    const int bh = blockIdx.y;         // 0..63
    const int b = bh >> 4, h = bh & 15;
    const long qrowbase = (long)b * 8192 + h;

    // Q A-fragments (d = 0..63 -> 2 frags), straight from global
    short8 Qf0, Qf1;
    {
        const int i = qt * 64 + wid * 16 + r;
        const u16* p = qkv + (qrowbase + (long)i * 16) * 192 + q * 8;
        Qf0 = *(const short8*)(p);
        Qf1 = *(const short8*)(p + 32);
    }

    // staging base pointers (this thread covers key/row = wid*16 + r, octet q)
    const u16* kbase = qkv + (qrowbase + (long)(wid * 16 + r) * 16) * 192
                           + 64 + q * 8;                 // + j0*3072 + f*32
    const u16* vbase = Vt + ((long)bh * 64 + wid * 16 + r) * 512 + q * 8;  // + j0 + f*32

    // prologue: stage chunk 0 into buf 0
    gld16(&Ks[0][wid * 64],       kbase);
    gld16(&Ks[0][256 + wid * 64], kbase + 32);
    gld16(&Vs[0][wid * 64],       vbase);
    gld16(&Vs[0][256 + wid * 64], vbase + 32);
    __syncthreads();

    f32x4 O[4] = {};
    float mrun[4] = {-1e30f, -1e30f, -1e30f, -1e30f};
    float lrun[4] = {};
    u16* Pw = &Plds[wid][0];

    for (int c = 0; c < 8; ++c) {
        const int j0 = c * 64, buf = c & 1;
        if (c < 7) {   // async prefetch next chunk into other buffer
            const u16* kp = kbase + (long)(j0 + 64) * 3072;
            const u16* vp = vbase + j0 + 64;
            gld16(&Ks[buf ^ 1][wid * 64],       kp);
            gld16(&Ks[buf ^ 1][256 + wid * 64], kp + 32);
            gld16(&Vs[buf ^ 1][wid * 64],       vp);
            gld16(&Vs[buf ^ 1][256 + wid * 64], vp + 32);
        }
        // ---- scores chunk S[16 rows][64 keys] ----
        f32x4 S[4];
        #pragma unroll
        for (int ct = 0; ct < 4; ++ct) {
            f32x4 s = {};
            s = __builtin_amdgcn_mfma_f32_16x16x32_bf16(
                Qf0, Ks[buf][ct * 64 + lane], s, 0, 0, 0);
            s = __builtin_amdgcn_mfma_f32_16x16x32_bf16(
                Qf1, Ks[buf][256 + ct * 64 + lane], s, 0, 0, 0);
            S[ct] = s;
        }
        // ---- online softmax update (row = (q,e); reduce over r, ct) ----
        #pragma unroll
        for (int e = 0; e < 4; ++e) {
            float mc = fmaxf(fmaxf(S[0][e], S[1][e]), fmaxf(S[2][e], S[3][e]));
            #pragma unroll
            for (int off = 1; off < 16; off <<= 1)
                mc = fmaxf(mc, __shfl_xor(mc, off, 64));
            const float mnew = fmaxf(mrun[e], mc);
            const float alpha = __expf(mrun[e] - mnew);
            mrun[e] = mnew;
            float se = 0.f;
            #pragma unroll
            for (int ct = 0; ct < 4; ++ct) {
                const float pv = __expf(S[ct][e] - mnew);
                S[ct][e] = pv; se += pv;
            }
            #pragma unroll
            for (int off = 1; off < 16; off <<= 1)
                se += __shfl_xor(se, off, 64);
            lrun[e] = lrun[e] * alpha + se;
            #pragma unroll
            for (int nt = 0; nt < 4; ++nt) O[nt][e] *= alpha;
        }
        // ---- P: C-layout -> LDS [m][k] (stride 72) -> A-frags ----
        #pragma unroll
        for (int e = 0; e < 4; ++e)
            #pragma unroll
            for (int ct = 0; ct < 4; ++ct)
                Pw[(q * 4 + e) * 72 + ct * 16 + r] = f2bf(S[ct][e]);
        short8 Pf0 = *(const short8*)(Pw + r * 72 + q * 8);
        short8 Pf1 = *(const short8*)(Pw + r * 72 + 32 + q * 8);
        // ---- O += P @ V ----
        #pragma unroll
        for (int nt = 0; nt < 4; ++nt) {
            O[nt] = __builtin_amdgcn_mfma_f32_16x16x32_bf16(
                Pf0, Vs[buf][nt * 64 + lane], O[nt], 0, 0, 0);
            O[nt] = __builtin_amdgcn_mfma_f32_16x16x32_bf16(
                Pf1, Vs[buf][256 + nt * 64 + lane], O[nt], 0, 0, 0);
        }
        __syncthreads();   // prefetch arrived + all waves done with buf
    }

    // ---- epilogue: normalize, write ctx[b*512+i][h*64+d] ----
    #pragma unroll
    for (int e = 0; e < 4; ++e) {
        const float inv = 1.0f / lrun[e];
        const long i = qt * 64 + wid * 16 + q * 4 + e;
        u16* po = ctx + ((long)b * 512 + i) * 1024 + h * 64 + r;
        #pragma unroll
        for (int nt = 0; nt < 4; ++nt)
            po[nt * 16] = f2bf(O[nt][e] * inv);
    }
}

// ---------------------------------------------------------------------------
// Output projection: out[2048][1024] fp32 = ctx @ Wob^T + bo.
// 64x64 tile, BK=64, both operands via global_load_lds, double-buffered.
// Waves 2x2; wave = 32m x 32n (2x2 MFMA tiles).
// ---------------------------------------------------------------------------
__global__ __launch_bounds__(256) void gemm_o(
    const u16* __restrict__ A, const u16* __restrict__ B,
    const float* __restrict__ bias, float* __restrict__ C)
{
    __shared__ short8 As[2][512];   // [f*256 + mt*64 + q*16 + r]
    __shared__ short8 Bs[2][512];

    const int tid = threadIdx.x;
    const int lane = tid & 63, wid = tid >> 6;
    const int q = lane >> 4, r = lane & 15;
    const long m0 = (long)blockIdx.x * 64, n0 = (long)blockIdx.y * 64;
    const int wm = wid >> 1, wn = wid & 1;

    // staging: thread i=0,1 -> section t = wid*2+i; f = t>>2, mt = t&3
    const u16* ap[2];
    const u16* bp[2];
    #pragma unroll
    for (int i = 0; i < 2; ++i) {
        const int t = wid * 2 + i, f = t >> 2, mt = t & 3;
        ap[i] = A + (m0 + mt * 16 + r) * 1024 + f * 32 + q * 8;
        bp[i] = B + (n0 + mt * 16 + r) * 1024 + f * 32 + q * 8;
    }

    #pragma unroll
    for (int i = 0; i < 2; ++i) {
        gld16(&As[0][(wid * 2 + i) * 64], ap[i]);
        gld16(&Bs[0][(wid * 2 + i) * 64], bp[i]);
    }
    __syncthreads();

    f32x4 acc[2][2] = {};

    for (int k0 = 0; k0 < 1024; k0 += 64) {
        const int buf = (k0 >> 6) & 1;
        if (k0 + 64 < 1024) {
            #pragma unroll
            for (int i = 0; i < 2; ++i) {
                gld16(&As[buf ^ 1][(wid * 2 + i) * 64], ap[i] + k0 + 64);
                gld16(&Bs[buf ^ 1][(wid * 2 + i) * 64], bp[i] + k0 + 64);
            }
        }
        #pragma unroll
        for (int f = 0; f < 2; ++f) {
            short8 af0 = As[buf][f * 256 + (wm * 2 + 0) * 64 + lane];
            short8 af1 = As[buf][f * 256 + (wm * 2 + 1) * 64 + lane];
            short8 bf0 = Bs[buf][f * 256 + (wn * 2 + 0) * 64 + lane];
            short8 bf1 = Bs[buf][f * 256 + (wn * 2 + 1) * 64 + lane];
            acc[0][0] = __builtin_amdgcn_mfma_f32_16x16x32_bf16(af0, bf0, acc[0][0], 0, 0, 0);
            acc[0][1] = __builtin_amdgcn_mfma_f32_16x16x32_bf16(af0, bf1, acc[0][1], 0, 0, 0);
            acc[1][0] = __builtin_amdgcn_mfma_f32_16x16x32_bf16(af1, bf0, acc[1][0], 0, 0, 0);
            acc[1][1] = __builtin_amdgcn_mfma_f32_16x16x32_bf16(af1, bf1, acc[1][1], 0, 0, 0);
        }
        __syncthreads();
    }

    #pragma unroll
    for (int i = 0; i < 2; ++i)
        #pragma unroll
        for (int j = 0; j < 2; ++j) {
            const long col = n0 + (wn * 2 + j) * 16 + r;
            const float badd = bias[col];
            #pragma unroll
            for (int e = 0; e < 4; ++e) {
                const long row = m0 + (wm * 2 + i) * 16 + q * 4 + e;
                C[row * 1024 + col] = acc[i][j][e] + badd;
            }
        }
}

// ---------------------------------------------------------------------------
extern "C" void kernel_launch(void* const* d_in, const int* in_sizes, int n_in,
                              void* d_out, int out_size, void* d_ws, size_t ws_size,
                              hipStream_t stream)
{
    const float* x  = (const float*)d_in[0];
    const float* Wq = (const float*)d_in[1];
    const float* bq = (const float*)d_in[2];
    const float* Wk = (const float*)d_in[3];
    const float* bk = (const float*)d_in[4];
    const float* Wv = (const float*)d_in[5];
    const float* bv = (const float*)d_in[6];
    const float* Wo = (const float*)d_in[7];
    const float* bo = (const float*)d_in[8];
    float* out = (float*)d_out;
    char* ws = (char*)d_ws;

    u16*   qkv  = (u16*)(ws);                   // 32768*192*2   = 12,582,912
    u16*   Vt   = (u16*)(ws + 12582912);        // 64*64*512*2   =  4,194,304
    u16*   Wqkv = (u16*)(ws + 16777216);        // 192*1024*2    =    393,216
    u16*   Wob  = (u16*)(ws + 17170432);        // 1024*1024*2   =  2,097,152
    float* qkvb = (float*)(ws + 19267584);      // 192*4
    u16*   ctx  = (u16*)(ws + 19268352);        // 2048*1024*2   =  4,194,304

    convw<<<4096, 256, 0, stream>>>(Wq, bq, Wk, bk, Wv, bv, Wo, Wqkv, qkvb, Wob);
    qkv_gemm<<<512, 256, 0, stream>>>(x, Wqkv, qkvb, qkv);
    vtrans<<<dim3(64, 8), 256, 0, stream>>>(qkv, Vt);
    attn_flash<<<dim3(8, 64), 256, 0, stream>>>(qkv, Vt, ctx);
    gemm_o<<<dim3(32, 16), 256, 0, stream>>>(ctx, Wob, bo, out);
}